// Round 3
// baseline (29948.181 us; speedup 1.0000x reference)
//
#include <hip/hip_runtime.h>

// Problem constants (B,T,S,L,D_IN,OUT,W = 256,512,256,36,8,10,256)
#define Tt   512
#define Ll   36
#define DIN  8
#define OUTd 10

typedef __attribute__((ext_vector_type(8))) short short8;
typedef __attribute__((ext_vector_type(4))) float f32x4;

__device__ __forceinline__ unsigned short f2bf(float f) {
    union { float f; unsigned int u; } v; v.f = f;
    unsigned int r = v.u + 0x7fffu + ((v.u >> 16) & 1u);   // RNE
    return (unsigned short)(r >> 16);
}
__device__ __forceinline__ float bf2f(unsigned short u) {
    union { unsigned int u; float f; } v; v.u = ((unsigned int)u) << 16;
    return v.f;
}
__device__ __forceinline__ float sp_f(float x) {      // jax.nn.softplus
    return fmaxf(x, 0.f) + __logf(1.f + __expf(-fabsf(x)));
}
__device__ __forceinline__ float tanh_f(float x) {
    float e = __expf(2.f * x);
    return 1.f - 2.f / (e + 1.f);
}

// ---- agent-scope (sc1 / LLC-coherent) access helpers: cross-XCD-safe without L2 invalidates ----
__device__ __forceinline__ unsigned long long ldg64(const void* p) {
    return __hip_atomic_load((const unsigned long long*)p, __ATOMIC_RELAXED, __HIP_MEMORY_SCOPE_AGENT);
}
__device__ __forceinline__ void stg64(void* p, unsigned long long v) {
    __hip_atomic_store((unsigned long long*)p, v, __ATOMIC_RELAXED, __HIP_MEMORY_SCOPE_AGENT);
}
__device__ __forceinline__ void stgf(float* p, float v) {
    __hip_atomic_store(p, v, __ATOMIC_RELAXED, __HIP_MEMORY_SCOPE_AGENT);
}
union U64F2 { unsigned long long u; float f[2]; unsigned short s[4]; };
union S8U   { unsigned long long u[2]; short8 v; };

// ---- LDS layout: union of per-phase scratch + persistent h-slice state ----
struct AScr { short hlh[16*264], hll[16*264], z1h[16*264], z1l[16*264], z2h[16*264], z2l[16*264]; };
struct CScr { short w3s[2][18432]; float lss[64*Ll]; float b3s[144]; };   // w3s: dbuf, frag-contig layout
struct RScr { float hs[16*260]; };
struct IScr { float x0s[32][DIN]; float h1[32*257]; float h2[32*257]; };
union  Scr  { AScr a; CScr c; RScr r; IScr in; };

// ---- grid barrier: 256 slots, relaxed sc1 flags; __syncthreads drains vmcnt pre-flag ----
__device__ __forceinline__ void gbar(int* slots, int gen) {
    __syncthreads();      // all waves drain their (sc1) stores -> LLC before flag
    const int tid = threadIdx.x;
    if (tid == 0)
        __hip_atomic_store(slots + blockIdx.x, gen, __ATOMIC_RELAXED, __HIP_MEMORY_SCOPE_AGENT);
    if (tid < 64) {
#pragma unroll 1
        for (int k = 0; k < 4; ++k) {
            while (__hip_atomic_load(slots + tid * 4 + k, __ATOMIC_RELAXED,
                                     __HIP_MEMORY_SCOPE_AGENT) < gen)
                __builtin_amdgcn_s_sleep(2);
        }
    }
    __syncthreads();
}

__device__ __forceinline__ void cast_quad(const float* src, unsigned short* dh,
                                          unsigned short* dl, long u) {
    f32x4 f = *(const f32x4*)(src + u * 4);
    U64F2 H, L;
#pragma unroll
    for (int q = 0; q < 4; ++q) {
        float v = f[q];
        unsigned short hi = f2bf(v);
        H.s[q] = hi;
        L.s[q] = f2bf(v - bf2f(hi));
    }
    stg64(dh + u * 4, H.u);
    stg64(dl + u * 4, L.u);
}

__global__ __launch_bounds__(256, 1) void rde_persistent(
    const float* __restrict__ x0, const float* __restrict__ logsigs,
    const float* __restrict__ iW1, const float* __restrict__ ib1,
    const float* __restrict__ iW2, const float* __restrict__ ib2,
    const float* __restrict__ iW3, const float* __restrict__ ib3,
    const float* __restrict__ vW1, const float* __restrict__ vb1,
    const float* __restrict__ vW2, const float* __restrict__ vb2,
    const float* __restrict__ vW3, const float* __restrict__ vb3,
    const float* __restrict__ roW, const float* __restrict__ rob,
    float* __restrict__ out,
    float* h, unsigned short* z2gh, unsigned short* z2gl,
    unsigned short* w1h, unsigned short* w1l,
    unsigned short* w2h, unsigned short* w2l,
    unsigned short* w3h, unsigned short* w3l, int* slots) {
    __shared__ Scr S;
    __shared__ float hloc[256];   // persistent h slice (64 rows x 4 s), exclusively owned
    __shared__ float hpart[256];
    const int tid = threadIdx.x, blk = blockIdx.x;
    const int lane = tid & 63, wv = tid >> 6, quad = lane >> 4, l15 = lane & 15;
    const int bch = blk >> 6, nsl = blk & 63;
    const int b0c = bch * 64, n0 = nsl * 144, s0 = nsl * 4;
    const f32x4 zero4 = {0.f, 0.f, 0.f, 0.f};
    int gen = 0;

    // ================= phase 0: init MLP (blk<8), W1/W2 cast (8..15), W3 cast (16..255) ======
    if (blk < 8) {
        IScr& I = S.in;
        const int b0 = blk * 32;
        I.x0s[tid >> 3][tid & 7] = x0[(b0 + (tid >> 3)) * DIN + (tid & 7)];
        __syncthreads();
        const int j = tid;
        {
            float w[DIN];
#pragma unroll
            for (int k = 0; k < DIN; ++k) w[k] = iW1[j * DIN + k];
            float bias = ib1[j];
            for (int r = 0; r < 32; ++r) {
                float acc = bias;
#pragma unroll
                for (int k = 0; k < DIN; ++k) acc += I.x0s[r][k] * w[k];
                I.h1[r * 257 + j] = sp_f(acc);
            }
        }
        __syncthreads();
        {
            float bias = ib2[j];
            for (int rb = 0; rb < 4; ++rb) {
                float a8[8];
#pragma unroll
                for (int rr = 0; rr < 8; ++rr) a8[rr] = bias;
                for (int k = 0; k < 256; ++k) {
                    float wvv = iW2[j * 256 + k];
#pragma unroll
                    for (int rr = 0; rr < 8; ++rr) a8[rr] += I.h1[(rb * 8 + rr) * 257 + k] * wvv;
                }
#pragma unroll
                for (int rr = 0; rr < 8; ++rr) I.h2[(rb * 8 + rr) * 257 + j] = sp_f(a8[rr]);
            }
        }
        __syncthreads();
        {
            float bias = ib3[j];
            for (int rb = 0; rb < 4; ++rb) {
                float a8[8];
#pragma unroll
                for (int rr = 0; rr < 8; ++rr) a8[rr] = bias;
                for (int k = 0; k < 256; ++k) {
                    float wvv = iW3[j * 256 + k];
#pragma unroll
                    for (int rr = 0; rr < 8; ++rr) a8[rr] += I.h2[(rb * 8 + rr) * 257 + k] * wvv;
                }
#pragma unroll
                for (int rr = 0; rr < 8; ++rr)
                    stgf(&h[(b0 + rb * 8 + rr) * 256 + j], a8[rr]);   // publish h0 to LLC
            }
        }
    } else if (blk < 16) {
        const int idx = blk - 8;
        const float* src = (idx < 4) ? vW1 : vW2;
        unsigned short* dh = (idx < 4) ? w1h : w2h;
        unsigned short* dl = (idx < 4) ? w1l : w2l;
        const int part = idx & 3;
        for (int u = part * 4096 + tid; u < (part + 1) * 4096; u += 256)
            cast_quad(src, dh, dl, u);
    } else {
        for (long u = (long)(blk - 16) * 256 + tid; u < 589824; u += 240L * 256)
            cast_quad(vW3, w3h, w3l, u);
    }
    gbar(slots, ++gen);

    // load persistent h slice (h0) once
    if (tid < 64) {
        U64F2 a, b;
        a.u = ldg64(h + (b0c + tid) * 256 + s0);
        b.u = ldg64(h + (b0c + tid) * 256 + s0 + 2);
        hloc[tid * 4 + 0] = a.f[0]; hloc[tid * 4 + 1] = a.f[1];
        hloc[tid * 4 + 2] = b.f[0]; hloc[tid * 4 + 3] = b.f[1];
    }

    // ================= main scan =================
    for (int t = 0; t < Tt; ++t) {
        // ---- phase A: blocks 0..15 compute z1,z2; blocks 16..31 readout out[:,t,:] ----
        if (blk < 16) {
            AScr& A = S.a;
            const int b0 = blk * 16;
            for (int u = tid; u < 2048; u += 256) {           // stage h rows (sc1) + hi/lo split
                int r = u >> 7, c = (u & 127) * 2;
                U64F2 vv; vv.u = ldg64(h + (b0 + r) * 256 + c);
#pragma unroll
                for (int q = 0; q < 2; ++q) {
                    float v = vv.f[q];
                    unsigned short hi = f2bf(v);
                    A.hlh[r * 264 + c + q] = (short)hi;
                    A.hll[r * 264 + c + q] = (short)f2bf(v - bf2f(hi));
                }
            }
            __syncthreads();
            {   // stage 1: z1 = sp(h W1^T)
                f32x4 acc[4] = {zero4, zero4, zero4, zero4};
                for (int k0 = 0; k0 < 256; k0 += 32) {
                    short8 ah = *(const short8*)(const void*)&A.hlh[l15 * 264 + k0 + quad * 8];
                    short8 al = *(const short8*)(const void*)&A.hll[l15 * 264 + k0 + quad * 8];
#pragma unroll
                    for (int j = 0; j < 4; ++j) {
                        int n = (4 * wv + j) * 16 + l15;
                        short8 bh = *(const short8*)(const void*)(w1h + n * 256 + k0 + quad * 8);
                        short8 bl = *(const short8*)(const void*)(w1l + n * 256 + k0 + quad * 8);
                        acc[j] = __builtin_amdgcn_mfma_f32_16x16x32_bf16(ah, bh, acc[j], 0, 0, 0);
                        acc[j] = __builtin_amdgcn_mfma_f32_16x16x32_bf16(ah, bl, acc[j], 0, 0, 0);
                        acc[j] = __builtin_amdgcn_mfma_f32_16x16x32_bf16(al, bh, acc[j], 0, 0, 0);
                    }
                }
#pragma unroll
                for (int j = 0; j < 4; ++j) {
                    int n = (4 * wv + j) * 16 + l15;
                    float bias = vb1[n];
#pragma unroll
                    for (int r = 0; r < 4; ++r) {
                        int row = quad * 4 + r;
                        float v = sp_f(acc[j][r] + bias);
                        unsigned short hi = f2bf(v);
                        A.z1h[row * 264 + n] = (short)hi;
                        A.z1l[row * 264 + n] = (short)f2bf(v - bf2f(hi));
                    }
                }
            }
            __syncthreads();
            {   // stage 2: z2 = sp(z1 W2^T) -> LDS
                f32x4 acc[4] = {zero4, zero4, zero4, zero4};
                for (int k0 = 0; k0 < 256; k0 += 32) {
                    short8 ah = *(const short8*)(const void*)&A.z1h[l15 * 264 + k0 + quad * 8];
                    short8 al = *(const short8*)(const void*)&A.z1l[l15 * 264 + k0 + quad * 8];
#pragma unroll
                    for (int j = 0; j < 4; ++j) {
                        int n = (4 * wv + j) * 16 + l15;
                        short8 bh = *(const short8*)(const void*)(w2h + n * 256 + k0 + quad * 8);
                        short8 bl = *(const short8*)(const void*)(w2l + n * 256 + k0 + quad * 8);
                        acc[j] = __builtin_amdgcn_mfma_f32_16x16x32_bf16(ah, bh, acc[j], 0, 0, 0);
                        acc[j] = __builtin_amdgcn_mfma_f32_16x16x32_bf16(ah, bl, acc[j], 0, 0, 0);
                        acc[j] = __builtin_amdgcn_mfma_f32_16x16x32_bf16(al, bh, acc[j], 0, 0, 0);
                    }
                }
#pragma unroll
                for (int j = 0; j < 4; ++j) {
                    int n = (4 * wv + j) * 16 + l15;
                    float bias = vb2[n];
#pragma unroll
                    for (int r = 0; r < 4; ++r) {
                        int row = quad * 4 + r;
                        float v = sp_f(acc[j][r] + bias);
                        unsigned short hi = f2bf(v);
                        A.z2h[row * 264 + n] = (short)hi;
                        A.z2l[row * 264 + n] = (short)f2bf(v - bf2f(hi));
                    }
                }
            }
            __syncthreads();
            for (int u = tid; u < 1024; u += 256) {           // publish z2 (coalesced sc1)
                int r = u >> 6, c = (u & 63) * 4;
                unsigned long long vh = *(const unsigned long long*)(const void*)&A.z2h[r * 264 + c];
                unsigned long long vl = *(const unsigned long long*)(const void*)&A.z2l[r * 264 + c];
                stg64(z2gh + (b0 + r) * 256 + c, vh);
                stg64(z2gl + (b0 + r) * 256 + c, vl);
            }
        } else if (blk < 32) {
            // ---- readout of out[:, t, :] from h_t (concurrent with A) ----
            RScr& R = S.r;
            const int i0 = (blk - 16) * 16;
            for (int u = tid; u < 2048; u += 256) {
                int r = u >> 7, c = (u & 127) * 2;
                U64F2 v; v.u = ldg64(h + (i0 + r) * 256 + c);
                R.hs[r * 260 + c] = v.f[0];
                R.hs[r * 260 + c + 1] = v.f[1];
            }
            __syncthreads();
            if (tid < 160) {
                int bl = tid / 10, o = tid - bl * 10;
                float acc = rob[o];
                const float* wp = roW + o * 256;
                for (int s = 0; s < 256; s += 4) {
                    f32x4 hv = *(const f32x4*)(const void*)&R.hs[bl * 260 + s];
                    f32x4 w4 = *(const f32x4*)(wp + s);
                    acc += hv[0] * w4[0] + hv[1] * w4[1] + hv[2] * w4[2] + hv[3] * w4[3];
                }
                out[((long)(i0 + bl) * 513 + t) * OUTd + o] = acc;
            }
        }
        gbar(slots, ++gen);

        // ---- phase C: all 256 blocks: m = tanh(z2 W3^T + b3); h += einsum(m, ls) ----
        {
            CScr& C = S.c;
            hpart[tid] = 0.f;
            for (int i = tid; i < 64 * Ll; i += 256) {
                int r = i / Ll, l = i - r * Ll;
                C.lss[i] = logsigs[((long)(b0c + r) * Tt + t) * Ll + l];
            }
            if (tid < 144) C.b3s[tid] = vb3[n0 + tid];
            // stage W3 chunk 0 (k 0..63) into buffer 0, frag-contiguous layout
            for (int u = tid; u < 2304; u += 256) {
                int isLo = (u >= 1152) ? 1 : 0;
                int uu = u - isLo * 1152;
                int r = uu >> 3, p = uu & 7;
                const unsigned short* src = isLo ? w3l : w3h;
                short8 v = *(const short8*)(const void*)(src + (long)(n0 + r) * 256 + p * 8);
                int d = ((p >> 2) * 9 + (r >> 4)) * 64 + (p & 3) * 16 + (r & 15);
                *(short8*)(void*)(C.w3s[0] + isLo * 9216 + d * 8) = v;
            }
            // prefetch z2 fragments for kk=0 (sc1, LLC)
            const int rz = b0c + 16 * wv + l15;
            long zb = (long)rz * 256 + quad * 8;
            unsigned long long ch0 = ldg64(z2gh + zb), ch1 = ldg64(z2gh + zb + 4);
            unsigned long long cl0 = ldg64(z2gl + zb), cl1 = ldg64(z2gl + zb + 4);
            __syncthreads();
            f32x4 acc[9];
#pragma unroll
            for (int nt = 0; nt < 9; ++nt) acc[nt] = zero4;
            for (int c4 = 0; c4 < 4; ++c4) {
                if (c4 < 3) {   // prefetch next W3 chunk into other buffer
                    for (int u = tid; u < 2304; u += 256) {
                        int isLo = (u >= 1152) ? 1 : 0;
                        int uu = u - isLo * 1152;
                        int r = uu >> 3, p = uu & 7;
                        const unsigned short* src = isLo ? w3l : w3h;
                        short8 v = *(const short8*)(const void*)(src + (long)(n0 + r) * 256 + (c4 + 1) * 64 + p * 8);
                        int d = ((p >> 2) * 9 + (r >> 4)) * 64 + (p & 3) * 16 + (r & 15);
                        *(short8*)(void*)(C.w3s[(c4 + 1) & 1] + isLo * 9216 + d * 8) = v;
                    }
                }
                const short* wb = C.w3s[c4 & 1];
#pragma unroll
                for (int sub = 0; sub < 2; ++sub) {
                    const int kk = c4 * 2 + sub;
                    S8U ah, al;
                    ah.u[0] = ch0; ah.u[1] = ch1;
                    al.u[0] = cl0; al.u[1] = cl1;
                    if (kk < 7) {
                        long nb = (long)rz * 256 + (kk + 1) * 32 + quad * 8;
                        ch0 = ldg64(z2gh + nb); ch1 = ldg64(z2gh + nb + 4);
                        cl0 = ldg64(z2gl + nb); cl1 = ldg64(z2gl + nb + 4);
                    }
#pragma unroll
                    for (int nt = 0; nt < 9; ++nt) {
                        const short* pp = wb + ((sub * 9 + nt) * 64 + lane) * 8;
                        short8 bh = *(const short8*)(const void*)pp;
                        short8 bl = *(const short8*)(const void*)(pp + 9216);
                        acc[nt] = __builtin_amdgcn_mfma_f32_16x16x32_bf16(ah.v, bh, acc[nt], 0, 0, 0);
                        acc[nt] = __builtin_amdgcn_mfma_f32_16x16x32_bf16(ah.v, bl, acc[nt], 0, 0, 0);
                        acc[nt] = __builtin_amdgcn_mfma_f32_16x16x32_bf16(al.v, bh, acc[nt], 0, 0, 0);
                    }
                }
                __syncthreads();
            }
            // epilogue: tanh + l-contraction via LDS atomics
#pragma unroll
            for (int nt = 0; nt < 9; ++nt) {
                int nl = nt * 16 + l15;
                float bias = C.b3s[nl];
                int sl = nl / 36, ll = nl - sl * 36;
#pragma unroll
                for (int r = 0; r < 4; ++r) {
                    int row = 16 * wv + quad * 4 + r;
                    float m = tanh_f(acc[nt][r] + bias);
                    atomicAdd(&hpart[row * 4 + sl], m * C.lss[row * 36 + ll]);
                }
            }
            __syncthreads();
            if (tid < 64) {   // h update + publish (exclusive owner)
                int row = tid;
                float v0 = hloc[row * 4 + 0] + hpart[row * 4 + 0];
                float v1 = hloc[row * 4 + 1] + hpart[row * 4 + 1];
                float v2 = hloc[row * 4 + 2] + hpart[row * 4 + 2];
                float v3 = hloc[row * 4 + 3] + hpart[row * 4 + 3];
                hloc[row * 4 + 0] = v0; hloc[row * 4 + 1] = v1;
                hloc[row * 4 + 2] = v2; hloc[row * 4 + 3] = v3;
                U64F2 p0, p1;
                p0.f[0] = v0; p0.f[1] = v1; p1.f[0] = v2; p1.f[1] = v3;
                stg64(h + (b0c + row) * 256 + s0, p0.u);
                stg64(h + (b0c + row) * 256 + s0 + 2, p1.u);
            }
        }
        gbar(slots, ++gen);
    }

    // ---- final readout out[:, 512, :] ----
    if (blk >= 16 && blk < 32) {
        RScr& R = S.r;
        const int i0 = (blk - 16) * 16;
        __syncthreads();
        for (int u = tid; u < 2048; u += 256) {
            int r = u >> 7, c = (u & 127) * 2;
            U64F2 v; v.u = ldg64(h + (i0 + r) * 256 + c);
            R.hs[r * 260 + c] = v.f[0];
            R.hs[r * 260 + c + 1] = v.f[1];
        }
        __syncthreads();
        if (tid < 160) {
            int bl = tid / 10, o = tid - bl * 10;
            float acc = rob[o];
            const float* wp = roW + o * 256;
            for (int s = 0; s < 256; s += 4) {
                f32x4 hv = *(const f32x4*)(const void*)&R.hs[bl * 260 + s];
                f32x4 w4 = *(const f32x4*)(wp + s);
                acc += hv[0] * w4[0] + hv[1] * w4[1] + hv[2] * w4[2] + hv[3] * w4[3];
            }
            out[((long)(i0 + bl) * 513 + Tt) * OUTd + o] = acc;
        }
    }
}

extern "C" void kernel_launch(void* const* d_in, const int* in_sizes, int n_in,
                              void* d_out, int out_size, void* d_ws, size_t ws_size,
                              hipStream_t stream) {
    const float* x0      = (const float*)d_in[0];
    const float* logsigs = (const float*)d_in[1];
    const float* iW1 = (const float*)d_in[2];
    const float* ib1 = (const float*)d_in[3];
    const float* iW2 = (const float*)d_in[4];
    const float* ib2 = (const float*)d_in[5];
    const float* iW3 = (const float*)d_in[6];
    const float* ib3 = (const float*)d_in[7];
    const float* vW1 = (const float*)d_in[8];
    const float* vb1 = (const float*)d_in[9];
    const float* vW2 = (const float*)d_in[10];
    const float* vb2 = (const float*)d_in[11];
    const float* vW3 = (const float*)d_in[12];
    const float* vb3 = (const float*)d_in[13];
    const float* roW = (const float*)d_in[14];
    const float* rob = (const float*)d_in[15];
    float* out = (float*)d_out;

    char* p = (char*)d_ws;
    float* h             = (float*)p;                         // 262144 B
    unsigned short* z2gh = (unsigned short*)(p + 262144);     // 131072 B
    unsigned short* z2gl = (unsigned short*)(p + 393216);     // 131072 B
    unsigned short* w1h  = (unsigned short*)(p + 524288);     // 131072 B
    unsigned short* w1l  = (unsigned short*)(p + 655360);     // 131072 B
    unsigned short* w2h  = (unsigned short*)(p + 786432);     // 131072 B
    unsigned short* w2l  = (unsigned short*)(p + 917504);     // 131072 B
    unsigned short* w3h  = (unsigned short*)(p + 1048576);    // 4718592 B
    unsigned short* w3l  = (unsigned short*)(p + 5767168);    // 4718592 B
    int* slots           = (int*)(p + 10485760);              // 1024 B

    hipMemsetAsync(slots, 0, 256 * sizeof(int), stream);
    rde_persistent<<<dim3(256), dim3(256), 0, stream>>>(
        x0, logsigs, iW1, ib1, iW2, ib2, iW3, ib3,
        vW1, vb1, vW2, vb2, vW3, vb3, roW, rob, out,
        h, z2gh, z2gl, w1h, w1l, w2h, w2l, w3h, w3l, slots);
}

// Round 4
// 21056.746 us; speedup vs baseline: 1.4223x; 1.4223x over previous
//
#include <hip/hip_runtime.h>

// Problem constants (B,T,S,L,D_IN,OUT,W = 256,512,256,36,8,10,256)
#define Tt   512
#define Ll   36
#define DIN  8
#define OUTd 10

typedef __attribute__((ext_vector_type(8))) short short8;
typedef __attribute__((ext_vector_type(4))) float f32x4;

__device__ __forceinline__ unsigned short f2bf(float f) {
    union { float f; unsigned int u; } v; v.f = f;
    unsigned int r = v.u + 0x7fffu + ((v.u >> 16) & 1u);   // RNE
    return (unsigned short)(r >> 16);
}
__device__ __forceinline__ float bf2f(unsigned short u) {
    union { unsigned int u; float f; } v; v.u = ((unsigned int)u) << 16;
    return v.f;
}
__device__ __forceinline__ float sp_f(float x) {      // jax.nn.softplus
    return fmaxf(x, 0.f) + __logf(1.f + __expf(-fabsf(x)));
}
__device__ __forceinline__ float tanh_f(float x) {
    float e = __expf(2.f * x);
    return 1.f - 2.f / (e + 1.f);
}

// ---- agent-scope (sc1 / LLC-coherent) helpers: cross-XCD-safe, bypass per-XCD L2 ----
__device__ __forceinline__ unsigned long long ldg64(const void* p) {
    return __hip_atomic_load((const unsigned long long*)p, __ATOMIC_RELAXED, __HIP_MEMORY_SCOPE_AGENT);
}
__device__ __forceinline__ void stg64(void* p, unsigned long long v) {
    __hip_atomic_store((unsigned long long*)p, v, __ATOMIC_RELAXED, __HIP_MEMORY_SCOPE_AGENT);
}
__device__ __forceinline__ void stgf(float* p, float v) {
    __hip_atomic_store(p, v, __ATOMIC_RELAXED, __HIP_MEMORY_SCOPE_AGENT);
}
union U64F2 { unsigned long long u; float f[2]; unsigned short s[4]; };
union S8U   { unsigned long long u[2]; short8 v; };

// ---- LDS layout: union of per-phase scratch + persistent h-slice state ----
struct AScr { short hlh[16*264], hll[16*264], z1h[16*264], z1l[16*264], z2h[16*264], z2l[16*264]; };
struct CScr { short w3s[2][18432]; float lss[64*Ll]; float ml[64*148]; float b3s[144]; };
struct RScr { float hs[16*260]; };
struct IScr { float x0s[32][DIN]; float h1[32*257]; float h2[32*257]; };
union  Scr  { AScr a; CScr c; RScr r; IScr in; };

// ---- tree grid barrier: 8 monotone group counters -> super counter -> release word.
// Only tid 0 polls (with s_sleep backoff) => no LLC poll storm. Data ordering: the entry
// __syncthreads drains each block's sc1 stores (vmcnt 0) before its arrive-add.
__device__ __forceinline__ void gbar(int* bar, int gen) {
    __syncthreads();
    if (threadIdx.x == 0) {
        const int g = blockIdx.x & 7;
        int old = __hip_atomic_fetch_add(bar + g * 32, 1, __ATOMIC_RELAXED, __HIP_MEMORY_SCOPE_AGENT);
        if (old == gen * 32 - 1) {                       // last block of this group
            int o2 = __hip_atomic_fetch_add(bar + 8 * 32, 1, __ATOMIC_RELAXED, __HIP_MEMORY_SCOPE_AGENT);
            if (o2 == gen * 8 - 1)                       // last group overall -> release
                __hip_atomic_store(bar + 9 * 32, gen, __ATOMIC_RELAXED, __HIP_MEMORY_SCOPE_AGENT);
        }
        while (__hip_atomic_load(bar + 9 * 32, __ATOMIC_RELAXED, __HIP_MEMORY_SCOPE_AGENT) < gen)
            __builtin_amdgcn_s_sleep(4);
    }
    __syncthreads();
}

__device__ __forceinline__ void cast_quad(const float* src, unsigned short* dh,
                                          unsigned short* dl, long u) {
    f32x4 f = *(const f32x4*)(src + u * 4);
    U64F2 H, L;
#pragma unroll
    for (int q = 0; q < 4; ++q) {
        float v = f[q];
        unsigned short hi = f2bf(v);
        H.s[q] = hi;
        L.s[q] = f2bf(v - bf2f(hi));
    }
    stg64(dh + u * 4, H.u);
    stg64(dl + u * 4, L.u);
}

__global__ __launch_bounds__(256, 1) void rde_persistent(
    const float* __restrict__ x0, const float* __restrict__ logsigs,
    const float* __restrict__ iW1, const float* __restrict__ ib1,
    const float* __restrict__ iW2, const float* __restrict__ ib2,
    const float* __restrict__ iW3, const float* __restrict__ ib3,
    const float* __restrict__ vW1, const float* __restrict__ vb1,
    const float* __restrict__ vW2, const float* __restrict__ vb2,
    const float* __restrict__ vW3, const float* __restrict__ vb3,
    const float* __restrict__ roW, const float* __restrict__ rob,
    float* __restrict__ out,
    float* h, unsigned short* z2gh, unsigned short* z2gl,
    unsigned short* w1h, unsigned short* w1l,
    unsigned short* w2h, unsigned short* w2l,
    unsigned short* w3h, unsigned short* w3l, int* slots) {
    __shared__ Scr S;
    __shared__ float hloc[256];   // persistent h slice (64 rows x 4 s), exclusively owned
    const int tid = threadIdx.x, blk = blockIdx.x;
    const int lane = tid & 63, wv = tid >> 6, quad = lane >> 4, l15 = lane & 15;
    const int bch = blk >> 6, nsl = blk & 63;
    const int b0c = bch * 64, n0 = nsl * 144, s0 = nsl * 4;
    const f32x4 zero4 = {0.f, 0.f, 0.f, 0.f};
    int gen = 0;

    // ================= phase 0: init MLP (blk<8), W1/W2 cast (8..15), W3 cast (16..255) ======
    if (blk < 8) {
        IScr& I = S.in;
        const int b0 = blk * 32;
        I.x0s[tid >> 3][tid & 7] = x0[(b0 + (tid >> 3)) * DIN + (tid & 7)];
        __syncthreads();
        const int j = tid;
        {
            float w[DIN];
#pragma unroll
            for (int k = 0; k < DIN; ++k) w[k] = iW1[j * DIN + k];
            float bias = ib1[j];
            for (int r = 0; r < 32; ++r) {
                float acc = bias;
#pragma unroll
                for (int k = 0; k < DIN; ++k) acc += I.x0s[r][k] * w[k];
                I.h1[r * 257 + j] = sp_f(acc);
            }
        }
        __syncthreads();
        {
            float bias = ib2[j];
            for (int rb = 0; rb < 4; ++rb) {
                float a8[8];
#pragma unroll
                for (int rr = 0; rr < 8; ++rr) a8[rr] = bias;
                for (int k = 0; k < 256; ++k) {
                    float wvv = iW2[j * 256 + k];
#pragma unroll
                    for (int rr = 0; rr < 8; ++rr) a8[rr] += I.h1[(rb * 8 + rr) * 257 + k] * wvv;
                }
#pragma unroll
                for (int rr = 0; rr < 8; ++rr) I.h2[(rb * 8 + rr) * 257 + j] = sp_f(a8[rr]);
            }
        }
        __syncthreads();
        {
            float bias = ib3[j];
            for (int rb = 0; rb < 4; ++rb) {
                float a8[8];
#pragma unroll
                for (int rr = 0; rr < 8; ++rr) a8[rr] = bias;
                for (int k = 0; k < 256; ++k) {
                    float wvv = iW3[j * 256 + k];
#pragma unroll
                    for (int rr = 0; rr < 8; ++rr) a8[rr] += I.h2[(rb * 8 + rr) * 257 + k] * wvv;
                }
#pragma unroll
                for (int rr = 0; rr < 8; ++rr)
                    stgf(&h[(b0 + rb * 8 + rr) * 256 + j], a8[rr]);   // publish h0 to LLC
            }
        }
    } else if (blk < 16) {
        const int idx = blk - 8;
        const float* src = (idx < 4) ? vW1 : vW2;
        unsigned short* dh = (idx < 4) ? w1h : w2h;
        unsigned short* dl = (idx < 4) ? w1l : w2l;
        const int part = idx & 3;
        for (int u = part * 4096 + tid; u < (part + 1) * 4096; u += 256)
            cast_quad(src, dh, dl, u);
    } else {
        for (long u = (long)(blk - 16) * 256 + tid; u < 589824; u += 240L * 256)
            cast_quad(vW3, w3h, w3l, u);
    }
    gbar(slots, ++gen);

    // load persistent h slice (h0) once
    if (tid < 64) {
        U64F2 a, b;
        a.u = ldg64(h + (b0c + tid) * 256 + s0);
        b.u = ldg64(h + (b0c + tid) * 256 + s0 + 2);
        hloc[tid * 4 + 0] = a.f[0]; hloc[tid * 4 + 1] = a.f[1];
        hloc[tid * 4 + 2] = b.f[0]; hloc[tid * 4 + 3] = b.f[1];
    }

    // ================= main scan =================
    for (int t = 0; t < Tt; ++t) {
        // ---- phase A: blocks 0..15 compute z1,z2; blocks 16..31 readout out[:,t,:] ----
        if (blk < 16) {
            AScr& A = S.a;
            const int b0 = blk * 16;
            for (int u = tid; u < 2048; u += 256) {           // stage h rows (sc1) + hi/lo split
                int r = u >> 7, c = (u & 127) * 2;
                U64F2 vv; vv.u = ldg64(h + (b0 + r) * 256 + c);
#pragma unroll
                for (int q = 0; q < 2; ++q) {
                    float v = vv.f[q];
                    unsigned short hi = f2bf(v);
                    A.hlh[r * 264 + c + q] = (short)hi;
                    A.hll[r * 264 + c + q] = (short)f2bf(v - bf2f(hi));
                }
            }
            __syncthreads();
            {   // stage 1: z1 = sp(h W1^T)
                f32x4 acc[4] = {zero4, zero4, zero4, zero4};
                for (int k0 = 0; k0 < 256; k0 += 32) {
                    short8 ah = *(const short8*)(const void*)&A.hlh[l15 * 264 + k0 + quad * 8];
                    short8 al = *(const short8*)(const void*)&A.hll[l15 * 264 + k0 + quad * 8];
#pragma unroll
                    for (int j = 0; j < 4; ++j) {
                        int n = (4 * wv + j) * 16 + l15;
                        short8 bh = *(const short8*)(const void*)(w1h + n * 256 + k0 + quad * 8);
                        short8 bl = *(const short8*)(const void*)(w1l + n * 256 + k0 + quad * 8);
                        acc[j] = __builtin_amdgcn_mfma_f32_16x16x32_bf16(ah, bh, acc[j], 0, 0, 0);
                        acc[j] = __builtin_amdgcn_mfma_f32_16x16x32_bf16(ah, bl, acc[j], 0, 0, 0);
                        acc[j] = __builtin_amdgcn_mfma_f32_16x16x32_bf16(al, bh, acc[j], 0, 0, 0);
                    }
                }
#pragma unroll
                for (int j = 0; j < 4; ++j) {
                    int n = (4 * wv + j) * 16 + l15;
                    float bias = vb1[n];
#pragma unroll
                    for (int r = 0; r < 4; ++r) {
                        int row = quad * 4 + r;
                        float v = sp_f(acc[j][r] + bias);
                        unsigned short hi = f2bf(v);
                        A.z1h[row * 264 + n] = (short)hi;
                        A.z1l[row * 264 + n] = (short)f2bf(v - bf2f(hi));
                    }
                }
            }
            __syncthreads();
            {   // stage 2: z2 = sp(z1 W2^T) -> LDS
                f32x4 acc[4] = {zero4, zero4, zero4, zero4};
                for (int k0 = 0; k0 < 256; k0 += 32) {
                    short8 ah = *(const short8*)(const void*)&A.z1h[l15 * 264 + k0 + quad * 8];
                    short8 al = *(const short8*)(const void*)&A.z1l[l15 * 264 + k0 + quad * 8];
#pragma unroll
                    for (int j = 0; j < 4; ++j) {
                        int n = (4 * wv + j) * 16 + l15;
                        short8 bh = *(const short8*)(const void*)(w2h + n * 256 + k0 + quad * 8);
                        short8 bl = *(const short8*)(const void*)(w2l + n * 256 + k0 + quad * 8);
                        acc[j] = __builtin_amdgcn_mfma_f32_16x16x32_bf16(ah, bh, acc[j], 0, 0, 0);
                        acc[j] = __builtin_amdgcn_mfma_f32_16x16x32_bf16(ah, bl, acc[j], 0, 0, 0);
                        acc[j] = __builtin_amdgcn_mfma_f32_16x16x32_bf16(al, bh, acc[j], 0, 0, 0);
                    }
                }
#pragma unroll
                for (int j = 0; j < 4; ++j) {
                    int n = (4 * wv + j) * 16 + l15;
                    float bias = vb2[n];
#pragma unroll
                    for (int r = 0; r < 4; ++r) {
                        int row = quad * 4 + r;
                        float v = sp_f(acc[j][r] + bias);
                        unsigned short hi = f2bf(v);
                        A.z2h[row * 264 + n] = (short)hi;
                        A.z2l[row * 264 + n] = (short)f2bf(v - bf2f(hi));
                    }
                }
            }
            __syncthreads();
            for (int u = tid; u < 1024; u += 256) {           // publish z2 (coalesced sc1)
                int r = u >> 6, c = (u & 63) * 4;
                unsigned long long vh = *(const unsigned long long*)(const void*)&A.z2h[r * 264 + c];
                unsigned long long vl = *(const unsigned long long*)(const void*)&A.z2l[r * 264 + c];
                stg64(z2gh + (b0 + r) * 256 + c, vh);
                stg64(z2gl + (b0 + r) * 256 + c, vl);
            }
        } else if (blk < 32) {
            // ---- readout of out[:, t, :] from h_t (concurrent with A) ----
            RScr& R = S.r;
            const int i0 = (blk - 16) * 16;
            for (int u = tid; u < 2048; u += 256) {
                int r = u >> 7, c = (u & 127) * 2;
                U64F2 v; v.u = ldg64(h + (i0 + r) * 256 + c);
                R.hs[r * 260 + c] = v.f[0];
                R.hs[r * 260 + c + 1] = v.f[1];
            }
            __syncthreads();
            if (tid < 160) {
                int bl = tid / 10, o = tid - bl * 10;
                float acc = rob[o];
                const float* wp = roW + o * 256;
                for (int s = 0; s < 256; s += 4) {
                    f32x4 hv = *(const f32x4*)(const void*)&R.hs[bl * 260 + s];
                    f32x4 w4 = *(const f32x4*)(wp + s);
                    acc += hv[0] * w4[0] + hv[1] * w4[1] + hv[2] * w4[2] + hv[3] * w4[3];
                }
                out[((long)(i0 + bl) * 513 + t) * OUTd + o] = acc;
            }
        }
        gbar(slots, ++gen);

        // ---- phase C: all 256 blocks: m = tanh(z2 W3^T + b3); h += einsum(m, ls) ----
        {
            CScr& C = S.c;
            for (int i = tid; i < 64 * Ll; i += 256) {
                int r = i / Ll, l = i - r * Ll;
                C.lss[i] = logsigs[((long)(b0c + r) * Tt + t) * Ll + l];
            }
            if (tid < 144) C.b3s[tid] = vb3[n0 + tid];
            // stage W3 chunk 0 (k 0..63) into buffer 0, frag-contiguous layout
            for (int u = tid; u < 2304; u += 256) {
                int isLo = (u >= 1152) ? 1 : 0;
                int uu = u - isLo * 1152;
                int r = uu >> 3, p = uu & 7;
                const unsigned short* src = isLo ? w3l : w3h;
                short8 v = *(const short8*)(const void*)(src + (long)(n0 + r) * 256 + p * 8);
                int d = ((p >> 2) * 9 + (r >> 4)) * 64 + (p & 3) * 16 + (r & 15);
                *(short8*)(void*)(C.w3s[0] + isLo * 9216 + d * 8) = v;
            }
            // preload ALL z2 fragments (complete during the staging __syncthreads -> no stalls)
            const int rz = b0c + 16 * wv + l15;
            unsigned long long zh[8][2], zl[8][2];
#pragma unroll
            for (int kk = 0; kk < 8; ++kk) {
                long nb = (long)rz * 256 + kk * 32 + quad * 8;
                zh[kk][0] = ldg64(z2gh + nb); zh[kk][1] = ldg64(z2gh + nb + 4);
                zl[kk][0] = ldg64(z2gl + nb); zl[kk][1] = ldg64(z2gl + nb + 4);
            }
            __syncthreads();
            f32x4 acc[9];
#pragma unroll
            for (int nt = 0; nt < 9; ++nt) acc[nt] = zero4;
#pragma unroll
            for (int c4 = 0; c4 < 4; ++c4) {
                if (c4 < 3) {   // prefetch next W3 chunk into other buffer
                    for (int u = tid; u < 2304; u += 256) {
                        int isLo = (u >= 1152) ? 1 : 0;
                        int uu = u - isLo * 1152;
                        int r = uu >> 3, p = uu & 7;
                        const unsigned short* src = isLo ? w3l : w3h;
                        short8 v = *(const short8*)(const void*)(src + (long)(n0 + r) * 256 + (c4 + 1) * 64 + p * 8);
                        int d = ((p >> 2) * 9 + (r >> 4)) * 64 + (p & 3) * 16 + (r & 15);
                        *(short8*)(void*)(C.w3s[(c4 + 1) & 1] + isLo * 9216 + d * 8) = v;
                    }
                }
                const short* wb = C.w3s[c4 & 1];
#pragma unroll
                for (int sub = 0; sub < 2; ++sub) {
                    const int kk = c4 * 2 + sub;
                    S8U ah, al;
                    ah.u[0] = zh[kk][0]; ah.u[1] = zh[kk][1];
                    al.u[0] = zl[kk][0]; al.u[1] = zl[kk][1];
#pragma unroll
                    for (int nt = 0; nt < 9; ++nt) {
                        const short* pp = wb + ((sub * 9 + nt) * 64 + lane) * 8;
                        short8 bh = *(const short8*)(const void*)pp;
                        short8 bl = *(const short8*)(const void*)(pp + 9216);
                        acc[nt] = __builtin_amdgcn_mfma_f32_16x16x32_bf16(ah.v, bh, acc[nt], 0, 0, 0);
                        acc[nt] = __builtin_amdgcn_mfma_f32_16x16x32_bf16(ah.v, bl, acc[nt], 0, 0, 0);
                        acc[nt] = __builtin_amdgcn_mfma_f32_16x16x32_bf16(al.v, bh, acc[nt], 0, 0, 0);
                    }
                }
                __syncthreads();
            }
            // epilogue: tanh -> ml (no LDS atomics)
#pragma unroll
            for (int nt = 0; nt < 9; ++nt) {
                int nl = nt * 16 + l15;
                float bias = C.b3s[nl];
#pragma unroll
                for (int r = 0; r < 4; ++r) {
                    int row = 16 * wv + quad * 4 + r;
                    C.ml[row * 148 + nl] = tanh_f(acc[nt][r] + bias);
                }
            }
            __syncthreads();
            // l-contraction: each thread owns one (row, sr): hloc[tid] += dot36
            {
                int row = tid >> 2, sr = tid & 3;
                const f32x4* mp = (const f32x4*)(const void*)&C.ml[row * 148 + sr * 36];
                const f32x4* lp = (const f32x4*)(const void*)&C.lss[row * 36];
                float a = 0.f;
#pragma unroll
                for (int q = 0; q < 9; ++q) {
                    f32x4 m4 = mp[q], l4 = lp[q];
                    a += m4[0] * l4[0] + m4[1] * l4[1] + m4[2] * l4[2] + m4[3] * l4[3];
                }
                hloc[tid] += a;
            }
            __syncthreads();
            if (tid < 64) {   // publish h slice (exclusive owner)
                U64F2 p0, p1;
                p0.f[0] = hloc[tid * 4 + 0]; p0.f[1] = hloc[tid * 4 + 1];
                p1.f[0] = hloc[tid * 4 + 2]; p1.f[1] = hloc[tid * 4 + 3];
                stg64(h + (b0c + tid) * 256 + s0, p0.u);
                stg64(h + (b0c + tid) * 256 + s0 + 2, p1.u);
            }
        }
        gbar(slots, ++gen);
    }

    // ---- final readout out[:, 512, :] ----
    if (blk >= 16 && blk < 32) {
        RScr& R = S.r;
        const int i0 = (blk - 16) * 16;
        __syncthreads();
        for (int u = tid; u < 2048; u += 256) {
            int r = u >> 7, c = (u & 127) * 2;
            U64F2 v; v.u = ldg64(h + (i0 + r) * 256 + c);
            R.hs[r * 260 + c] = v.f[0];
            R.hs[r * 260 + c + 1] = v.f[1];
        }
        __syncthreads();
        if (tid < 160) {
            int bl = tid / 10, o = tid - bl * 10;
            float acc = rob[o];
            const float* wp = roW + o * 256;
            for (int s = 0; s < 256; s += 4) {
                f32x4 hv = *(const f32x4*)(const void*)&R.hs[bl * 260 + s];
                f32x4 w4 = *(const f32x4*)(wp + s);
                acc += hv[0] * w4[0] + hv[1] * w4[1] + hv[2] * w4[2] + hv[3] * w4[3];
            }
            out[((long)(i0 + bl) * 513 + Tt) * OUTd + o] = acc;
        }
    }
}

extern "C" void kernel_launch(void* const* d_in, const int* in_sizes, int n_in,
                              void* d_out, int out_size, void* d_ws, size_t ws_size,
                              hipStream_t stream) {
    const float* x0      = (const float*)d_in[0];
    const float* logsigs = (const float*)d_in[1];
    const float* iW1 = (const float*)d_in[2];
    const float* ib1 = (const float*)d_in[3];
    const float* iW2 = (const float*)d_in[4];
    const float* ib2 = (const float*)d_in[5];
    const float* iW3 = (const float*)d_in[6];
    const float* ib3 = (const float*)d_in[7];
    const float* vW1 = (const float*)d_in[8];
    const float* vb1 = (const float*)d_in[9];
    const float* vW2 = (const float*)d_in[10];
    const float* vb2 = (const float*)d_in[11];
    const float* vW3 = (const float*)d_in[12];
    const float* vb3 = (const float*)d_in[13];
    const float* roW = (const float*)d_in[14];
    const float* rob = (const float*)d_in[15];
    float* out = (float*)d_out;

    char* p = (char*)d_ws;
    float* h             = (float*)p;                         // 262144 B
    unsigned short* z2gh = (unsigned short*)(p + 262144);     // 131072 B
    unsigned short* z2gl = (unsigned short*)(p + 393216);     // 131072 B
    unsigned short* w1h  = (unsigned short*)(p + 524288);     // 131072 B
    unsigned short* w1l  = (unsigned short*)(p + 655360);     // 131072 B
    unsigned short* w2h  = (unsigned short*)(p + 786432);     // 131072 B
    unsigned short* w2l  = (unsigned short*)(p + 917504);     // 131072 B
    unsigned short* w3h  = (unsigned short*)(p + 1048576);    // 4718592 B
    unsigned short* w3l  = (unsigned short*)(p + 5767168);    // 4718592 B
    int* slots           = (int*)(p + 10485760);              // barrier tree (>=1280 B)

    hipMemsetAsync(slots, 0, 4096, stream);
    rde_persistent<<<dim3(256), dim3(256), 0, stream>>>(
        x0, logsigs, iW1, ib1, iW2, ib2, iW3, ib3,
        vW1, vb1, vW2, vb2, vW3, vb3, roW, rob, out,
        h, z2gh, z2gl, w1h, w1l, w2h, w2l, w3h, w3l, slots);
}